// Round 4
// baseline (683.798 us; speedup 1.0000x reference)
//
#include <hip/hip_runtime.h>
#include <math.h>

#define FN 512
#define TPB 256
#define NIMG 256
#define NBATCH 8
#define NCH 32
#define NBINS 257
#define SPITCH 516   // staging row pitch (complex); byte stride 4128 -> +8 bank stagger per row

typedef unsigned long long ull;

__device__ __forceinline__ float2 cadd(float2 a, float2 b) { return make_float2(a.x + b.x, a.y + b.y); }
__device__ __forceinline__ float2 csub(float2 a, float2 b) { return make_float2(a.x - b.x, a.y - b.y); }
__device__ __forceinline__ float2 cmul(float2 a, float2 b) {
  return make_float2(fmaf(a.x, b.x, -a.y * b.y), fmaf(a.x, b.y, a.y * b.x));
}
// multiply by w (INV=false) or by conj(w) (INV=true)
template<bool INV>
__device__ __forceinline__ float2 cmul_s(float2 a, float2 w) {
  if (!INV) return make_float2(fmaf(a.x, w.x, -a.y * w.y), fmaf(a.x, w.y,  a.y * w.x));
  else      return make_float2(fmaf(a.x, w.x,  a.y * w.y), fmaf(a.y, w.x, -a.x * w.y));
}
__device__ __forceinline__ float2 cexpm(float ang) {
  float s, c;
  __sincosf(ang, &s, &c);
  return make_float2(c, s);
}
// multiply by -i (fwd) / +i (inv)
template<bool INV>
__device__ __forceinline__ float2 mulpmi(float2 a) {
  return INV ? make_float2(-a.y, a.x) : make_float2(a.y, -a.x);
}

// natural-order 8-point DFT in registers; INV=conjugate kernel (no 1/8)
template<bool INV>
__device__ __forceinline__ void dft8(float2 r[8]) {
  const float C = 0.70710678118654752440f;
  float2 t0 = cadd(r[0], r[4]), t1 = csub(r[0], r[4]);
  float2 t2 = cadd(r[2], r[6]), t3 = mulpmi<INV>(csub(r[2], r[6]));
  float2 E0 = cadd(t0, t2), E1 = cadd(t1, t3), E2 = csub(t0, t2), E3 = csub(t1, t3);
  float2 u0 = cadd(r[1], r[5]), u1 = csub(r[1], r[5]);
  float2 u2 = cadd(r[3], r[7]), u3 = mulpmi<INV>(csub(r[3], r[7]));
  float2 O0 = cadd(u0, u2), O1 = cadd(u1, u3), O2 = csub(u0, u2), O3 = csub(u1, u3);
  float2 O1w, O2w, O3w;
  if (!INV) {
    O1w = make_float2(C * (O1.x + O1.y), C * (O1.y - O1.x));   // *w8^1
    O2w = make_float2(O2.y, -O2.x);                            // *-i
    O3w = make_float2(C * (O3.y - O3.x), -C * (O3.x + O3.y));  // *w8^3
  } else {
    O1w = make_float2(C * (O1.x - O1.y), C * (O1.y + O1.x));
    O2w = make_float2(-O2.y, O2.x);
    O3w = make_float2(-C * (O3.x + O3.y), C * (O3.x - O3.y));
  }
  r[0] = cadd(E0, O0); r[1] = cadd(E1, O1w); r[2] = cadd(E2, O2w); r[3] = cadd(E3, O3w);
  r[4] = csub(E0, O0); r[5] = csub(E1, O1w); r[6] = csub(E2, O2w); r[7] = csub(E3, O3w);
}

// LDS exchange swizzle: XOR the 64-block digit into bits [3:0] -> all 4 exchange
// patterns become conflict-free (<=2 lanes/bank). Bijective within each 512 block.
__device__ __forceinline__ int swz(int q) {
  int b = (q >> 6) & 7;
  return q ^ b ^ ((b & 4) << 1);
}

#define TWOPI 6.2831853071795864769f

// Hoisted forward twiddles (t-dependent only): tw512[k-1] = W512^{-t*k}, tw64[e-1] = W64^{-(t&7)*e}
__device__ __forceinline__ void build_tw(int t, float2 tw512[7], float2 tw64[7]) {
  float2 w1 = cexpm(-TWOPI * (float)t * (1.0f / 512.0f));
  tw512[0] = w1;
  #pragma unroll
  for (int k = 1; k < 7; ++k) tw512[k] = cmul(tw512[k - 1], w1);
  float2 v1 = cexpm(-TWOPI * (float)(t & 7) * (1.0f / 64.0f));
  tw64[0] = v1;
  #pragma unroll
  for (int e = 1; e < 7; ++e) tw64[e] = cmul(tw64[e - 1], v1);
}

// 512-pt FFT, natural input (reg j = x[t+64j]) -> digit-reversed output:
// reg f = X[64f + 8(t&7) + (t>>3)]. INV=false: DFT; INV=true: 512*IDFT (twiddles conj'd).
// L = this wave's private 512-complex exchange region; all LDS ops wave-internal -> no barriers.
template<bool INV>
__device__ __forceinline__ void fft512_dif(float2 r[8], float2* __restrict__ L, int t,
                                           const float2 tw512[7], const float2 tw64[7]) {
  dft8<INV>(r);
  #pragma unroll
  for (int k = 1; k < 8; ++k) r[k] = cmul_s<INV>(r[k], tw512[k - 1]);
  #pragma unroll
  for (int k = 0; k < 8; ++k) L[swz(64 * k + t)] = r[k];
  {
    const int base = 64 * (t >> 3) + (t & 7);
    #pragma unroll
    for (int d = 0; d < 8; ++d) r[d] = L[swz(base + 8 * d)];
  }
  dft8<INV>(r);
  #pragma unroll
  for (int e = 1; e < 8; ++e) r[e] = cmul_s<INV>(r[e], tw64[e - 1]);
  {
    const int base = 64 * (t >> 3) + (t & 7);
    #pragma unroll
    for (int e = 0; e < 8; ++e) L[swz(base + 8 * e)] = r[e];
  }
  #pragma unroll
  for (int m = 0; m < 8; ++m) r[m] = L[swz(8 * t + m)];
  dft8<INV>(r);
}

// Mirror (DIT): digit-reversed input -> natural output. INV=true gives 512*IDFT.
template<bool INV>
__device__ __forceinline__ void fft512_dit(float2 r[8], float2* __restrict__ L, int t,
                                           const float2 tw64[7]) {
  const float SG = INV ? TWOPI : -TWOPI;
  dft8<INV>(r);  // over f -> reg c
  #pragma unroll
  for (int c = 1; c < 8; ++c) r[c] = cmul_s<INV>(r[c], tw64[c - 1]);
  #pragma unroll
  for (int c = 0; c < 8; ++c) L[swz(8 * t + c)] = r[c];
  {
    const int base = 64 * (t >> 3) + (t & 7);
    #pragma unroll
    for (int e = 0; e < 8; ++e) r[e] = L[swz(base + 8 * e)];
  }
  dft8<INV>(r);  // over e -> reg d
  {
    const int k = t >> 3, c = t & 7;
    float2 w = cexpm(SG * (float)(c * k) * (1.0f / 512.0f));
    float2 st = cexpm(SG * (float)k * (1.0f / 64.0f));
    #pragma unroll
    for (int d = 0; d < 8; ++d) { r[d] = cmul(r[d], w); w = cmul(w, st); }
  }
  {
    const int base = 64 * (t >> 3) + (t & 7);
    #pragma unroll
    for (int d = 0; d < 8; ++d) L[swz(base + 8 * d)] = r[d];
  }
  #pragma unroll
  for (int j = 0; j < 8; ++j) r[j] = L[swz(64 * j + t)];
  dft8<INV>(r);  // over k -> reg j (natural)
}

__device__ __forceinline__ int ringc(int u) { return (u < 256) ? (u + 1) : (512 - u); }

// Pass 1 (and pre-pass): real rows -> forward FFT -> transposed store W[u][r] (natural u).
__global__ __launch_bounds__(TPB) void k_fwd_real(const float* __restrict__ x,
                                                  float2* __restrict__ W,
                                                  int img0, int img_stride) {
  __shared__ float2 stg[8][SPITCH];
  const int g = threadIdx.x >> 6, t = threadIdx.x & 63;
  const int li = blockIdx.x >> 6;
  const int R0 = (blockIdx.x & 63) * 8;
  const int img = img0 + li * img_stride;
  const float* __restrict__ base = x + (size_t)img * (FN * FN);
  float2 tw512[7], tw64[7];
  build_tw(t, tw512, tw64);
  #pragma unroll
  for (int s = 0; s < 2; ++s) {
    const int rl = 4 * s + g;
    const float* __restrict__ row = base + (size_t)(R0 + rl) * FN;
    float2 r[8];
    #pragma unroll
    for (int j = 0; j < 8; ++j) r[j] = make_float2(row[t + 64 * j], 0.0f);
    fft512_dif<false>(r, &stg[rl][0], t, tw512, tw64);
    #pragma unroll
    for (int f = 0; f < 8; ++f) stg[rl][64 * f + 8 * (t & 7) + (t >> 3)] = r[f];
  }
  __syncthreads();
  float2* __restrict__ dst = W + (size_t)li * (FN * FN);
  const int rl2 = threadIdx.x & 3;
  const int ug0 = threadIdx.x >> 2;
  #pragma unroll
  for (int k = 0; k < 8; ++k) {
    int u = ug0 + 64 * k;
    float2 a = stg[2 * rl2][u];
    float2 b = stg[2 * rl2 + 1][u];
    float4* d4 = (float4*)(dst + (size_t)u * FN + R0);
    d4[rl2] = make_float4(a.x, a.y, b.x, b.y);
  }
}

// Pre-pass 2: FFT along h on channel-0 spectra rows; bin |F|^2 into rings (fixed-point).
__global__ __launch_bounds__(TPB) void k_ring(const float2* __restrict__ W1p, ull* __restrict__ bins) {
  __shared__ float2 ex[4][FN];
  __shared__ ull lbins[NBINS];
  const int g = threadIdx.x >> 6, t = threadIdx.x & 63;
  for (int i = threadIdx.x; i < NBINS; i += TPB) lbins[i] = 0;
  __syncthreads();
  const int li = blockIdx.x >> 6;
  const int V0 = (blockIdx.x & 63) * 8;
  const float2* __restrict__ src = W1p + (size_t)li * (FN * FN);
  float2 tw512[7], tw64[7];
  build_tw(t, tw512, tw64);
  #pragma unroll
  for (int s = 0; s < 2; ++s) {
    const int uw = V0 + 4 * s + g;
    const float2* __restrict__ row = src + (size_t)uw * FN;
    float2 r[8];
    #pragma unroll
    for (int j = 0; j < 8; ++j) r[j] = row[t + 64 * j];
    fft512_dif<false>(r, &ex[g][0], t, tw512, tw64);
    const int cw = ringc(uw);
    #pragma unroll
    for (int f = 0; f < 8; ++f) {
      int uh = 64 * f + 8 * (t & 7) + (t >> 3);
      int sr = max(cw, ringc(uh));
      float e = fmaf(r[f].x, r[f].x, r[f].y * r[f].y);
      atomicAdd(&lbins[sr], (ull)((double)e * 1048576.0));
    }
  }
  __syncthreads();
  for (int i = threadIdx.x; i < NBINS; i += TPB)
    if (lbins[i]) atomicAdd(&bins[(size_t)li * NBINS + i], lbins[i]);
}

__global__ __launch_bounds__(64) void k_cutoff(const ull* __restrict__ bins, int* __restrict__ cut) {
  int b = threadIdx.x;
  if (b >= NBATCH) return;
  double tot = 0.0;
  for (int r = 0; r < NBINS; ++r) tot += (double)bins[b * NBINS + r];
  double target = 0.5 * tot;
  double cum = 0.0;
  int c = 5;
  bool found = false;
  for (int r = 0; r <= 255; ++r) {
    cum += (double)bins[b * NBINS + r];
    if (r >= 1 && !found && cum >= target) { c = r; found = true; }
  }
  cut[b] = c;
}

// Pass 2: fwd FFT along h -> mask in registers -> inverse FFT -> transposed store Wb[h][uw].
__global__ __launch_bounds__(TPB) void k_mask(const float2* __restrict__ Wa, float2* __restrict__ Wb,
                                              const int* __restrict__ cut, int img0) {
  __shared__ float2 stg[8][SPITCH];
  const int g = threadIdx.x >> 6, t = threadIdx.x & 63;
  const int li = blockIdx.x >> 6;
  const int V0 = (blockIdx.x & 63) * 8;
  const int img = img0 + li;
  const int cutoff = cut[img >> 5];
  const float2* __restrict__ src = Wa + (size_t)li * (FN * FN);
  float2 tw512[7], tw64[7];
  build_tw(t, tw512, tw64);
  #pragma unroll
  for (int s = 0; s < 2; ++s) {
    const int rl = 4 * s + g;
    const int uw = V0 + rl;
    const float2* __restrict__ row = src + (size_t)uw * FN;
    float2 r[8];
    #pragma unroll
    for (int j = 0; j < 8; ++j) r[j] = row[t + 64 * j];
    float2* L = &stg[rl][0];
    fft512_dif<false>(r, L, t, tw512, tw64);
    const int cw = ringc(uw);
    #pragma unroll
    for (int f = 0; f < 8; ++f) {
      int uh = 64 * f + 8 * (t & 7) + (t >> 3);
      float m = (max(cw, ringc(uh)) > cutoff) ? (1.0f / 512.0f) : 0.0f;  // fold axis 1/N
      r[f].x *= m; r[f].y *= m;
    }
    fft512_dit<true>(r, L, t, tw64);
    #pragma unroll
    for (int j = 0; j < 8; ++j) stg[rl][t + 64 * j] = r[j];
  }
  __syncthreads();
  float2* __restrict__ dst = Wb + (size_t)li * (FN * FN);
  const int rl2 = threadIdx.x & 3;
  const int ug0 = threadIdx.x >> 2;
  #pragma unroll
  for (int k = 0; k < 8; ++k) {
    int n = ug0 + 64 * k;
    float2 a = stg[2 * rl2][n];
    float2 b = stg[2 * rl2 + 1][n];
    float4* d4 = (float4*)(dst + (size_t)n * FN + V0);
    d4[rl2] = make_float4(a.x, a.y, b.x, b.y);
  }
}

// Pass 3: inverse FFT along w -> |y|/512 -> direct store (digit-rev positions, coalesced 256B).
__global__ __launch_bounds__(TPB) void k_inv_abs(const float2* __restrict__ Wb, float* __restrict__ out,
                                                 int img0) {
  __shared__ float2 ex[4][FN];
  const int g = threadIdx.x >> 6, t = threadIdx.x & 63;
  const int li = blockIdx.x >> 6;
  const int H0 = (blockIdx.x & 63) * 8;
  const int img = img0 + li;
  const float2* __restrict__ src = Wb + (size_t)li * (FN * FN);
  float* __restrict__ obase = out + (size_t)img * (FN * FN);
  float2 tw512[7], tw64[7];
  build_tw(t, tw512, tw64);
  #pragma unroll
  for (int s = 0; s < 2; ++s) {
    const int h = H0 + 4 * s + g;
    const float2* __restrict__ row = src + (size_t)h * FN;
    float2 r[8];
    #pragma unroll
    for (int j = 0; j < 8; ++j) r[j] = row[t + 64 * j];
    fft512_dif<true>(r, &ex[g][0], t, tw512, tw64);
    float* __restrict__ orow = obase + (size_t)h * FN;
    const float sc = 1.0f / 512.0f;
    #pragma unroll
    for (int f = 0; f < 8; ++f) {
      int p = 64 * f + 8 * (t & 7) + (t >> 3);
      orow[p] = sqrtf(fmaf(r[f].x, r[f].x, r[f].y * r[f].y)) * sc;
    }
  }
}

extern "C" void kernel_launch(void* const* d_in, const int* in_sizes, int n_in,
                              void* d_out, int out_size, void* d_ws, size_t ws_size,
                              hipStream_t stream) {
  const float* x = (const float*)d_in[0];
  float* out = (float*)d_out;
  char* ws = (char*)d_ws;

  size_t off = 0;
  ull* bins = (ull*)(ws + off);
  off += ((size_t)NBATCH * NBINS * sizeof(ull) + 255) & ~(size_t)255;
  int* cut = (int*)(ws + off);
  off += 256;
  float2* W1p = (float2*)(ws + off);
  off += (size_t)NBATCH * FN * FN * sizeof(float2);  // 16 MiB

  const size_t per_img = (size_t)FN * FN * sizeof(float2);  // 2 MiB
  size_t avail = (ws_size > off) ? (ws_size - off) : 0;
  int K = (int)(avail / (2 * per_img));
  if (K > NIMG) K = NIMG;   // single-chunk if ws allows: big dispatches, visible counters
  if (K < 1) K = 1;
  float2* WA = (float2*)(ws + off);
  float2* WB = (float2*)(ws + off + (size_t)K * per_img);

  hipMemsetAsync(bins, 0, (size_t)NBATCH * NBINS * sizeof(ull), stream);

  // Pre-pass on the 8 channel-0 images: forward 2D FFT + ring energies + cutoffs.
  hipLaunchKernelGGL(k_fwd_real, dim3(NBATCH * 64), dim3(TPB), 0, stream, x, W1p, 0, NCH);
  hipLaunchKernelGGL(k_ring,     dim3(NBATCH * 64), dim3(TPB), 0, stream, W1p, bins);
  hipLaunchKernelGGL(k_cutoff,   dim3(1),           dim3(64),  0, stream, bins, cut);

  // Main pipeline, chunked to fit workspace.
  for (int c0 = 0; c0 < NIMG; c0 += K) {
    int nk = (NIMG - c0 < K) ? (NIMG - c0) : K;
    hipLaunchKernelGGL(k_fwd_real, dim3(nk * 64), dim3(TPB), 0, stream, x, WA, c0, 1);
    hipLaunchKernelGGL(k_mask,     dim3(nk * 64), dim3(TPB), 0, stream, WA, WB, cut, c0);
    hipLaunchKernelGGL(k_inv_abs,  dim3(nk * 64), dim3(TPB), 0, stream, WB, out, c0);
  }
}

// Round 5
// 569.974 us; speedup vs baseline: 1.1997x; 1.1997x over previous
//
#include <hip/hip_runtime.h>
#include <math.h>

#define FN 512
#define TPB 256
#define NIMG 256
#define NBATCH 8
#define NCH 32
#define NBINS 257
#define WACOLS 257   // Hermitian half-spectrum columns u=0..256
#define SPITCH 516   // staging row pitch (complex)

typedef unsigned long long ull;

__device__ __forceinline__ float2 cadd(float2 a, float2 b) { return make_float2(a.x + b.x, a.y + b.y); }
__device__ __forceinline__ float2 csub(float2 a, float2 b) { return make_float2(a.x - b.x, a.y - b.y); }
__device__ __forceinline__ float2 cmul(float2 a, float2 b) {
  return make_float2(fmaf(a.x, b.x, -a.y * b.y), fmaf(a.x, b.y, a.y * b.x));
}
// multiply by w (INV=false) or by conj(w) (INV=true)
template<bool INV>
__device__ __forceinline__ float2 cmul_s(float2 a, float2 w) {
  if (!INV) return make_float2(fmaf(a.x, w.x, -a.y * w.y), fmaf(a.x, w.y,  a.y * w.x));
  else      return make_float2(fmaf(a.x, w.x,  a.y * w.y), fmaf(a.y, w.x, -a.x * w.y));
}
__device__ __forceinline__ float2 cexpm(float ang) {
  float s, c;
  __sincosf(ang, &s, &c);
  return make_float2(c, s);
}
template<bool INV>
__device__ __forceinline__ float2 mulpmi(float2 a) {
  return INV ? make_float2(-a.y, a.x) : make_float2(a.y, -a.x);
}

template<bool INV>
__device__ __forceinline__ void dft8(float2 r[8]) {
  const float C = 0.70710678118654752440f;
  float2 t0 = cadd(r[0], r[4]), t1 = csub(r[0], r[4]);
  float2 t2 = cadd(r[2], r[6]), t3 = mulpmi<INV>(csub(r[2], r[6]));
  float2 E0 = cadd(t0, t2), E1 = cadd(t1, t3), E2 = csub(t0, t2), E3 = csub(t1, t3);
  float2 u0 = cadd(r[1], r[5]), u1 = csub(r[1], r[5]);
  float2 u2 = cadd(r[3], r[7]), u3 = mulpmi<INV>(csub(r[3], r[7]));
  float2 O0 = cadd(u0, u2), O1 = cadd(u1, u3), O2 = csub(u0, u2), O3 = csub(u1, u3);
  float2 O1w, O2w, O3w;
  if (!INV) {
    O1w = make_float2(C * (O1.x + O1.y), C * (O1.y - O1.x));
    O2w = make_float2(O2.y, -O2.x);
    O3w = make_float2(C * (O3.y - O3.x), -C * (O3.x + O3.y));
  } else {
    O1w = make_float2(C * (O1.x - O1.y), C * (O1.y + O1.x));
    O2w = make_float2(-O2.y, O2.x);
    O3w = make_float2(-C * (O3.x + O3.y), C * (O3.x - O3.y));
  }
  r[0] = cadd(E0, O0); r[1] = cadd(E1, O1w); r[2] = cadd(E2, O2w); r[3] = cadd(E3, O3w);
  r[4] = csub(E0, O0); r[5] = csub(E1, O1w); r[6] = csub(E2, O2w); r[7] = csub(E3, O3w);
}

// LDS exchange swizzle (bijective within each 512 block)
__device__ __forceinline__ int swz(int q) {
  int b = (q >> 6) & 7;
  return q ^ b ^ ((b & 4) << 1);
}

#define TWOPI 6.2831853071795864769f

__device__ __forceinline__ void build_tw(int t, float2 tw512[7], float2 tw64[7]) {
  float2 w1 = cexpm(-TWOPI * (float)t * (1.0f / 512.0f));
  tw512[0] = w1;
  #pragma unroll
  for (int k = 1; k < 7; ++k) tw512[k] = cmul(tw512[k - 1], w1);
  float2 v1 = cexpm(-TWOPI * (float)(t & 7) * (1.0f / 64.0f));
  tw64[0] = v1;
  #pragma unroll
  for (int e = 1; e < 7; ++e) tw64[e] = cmul(tw64[e - 1], v1);
}

// 512-pt FFT, natural in (reg j = x[t+64j]) -> digit-rev out (reg f = X[64f+8(t&7)+(t>>3)]).
// Wave-private exchange region, no barriers.
template<bool INV>
__device__ __forceinline__ void fft512_dif(float2 r[8], float2* __restrict__ L, int t,
                                           const float2 tw512[7], const float2 tw64[7]) {
  dft8<INV>(r);
  #pragma unroll
  for (int k = 1; k < 8; ++k) r[k] = cmul_s<INV>(r[k], tw512[k - 1]);
  #pragma unroll
  for (int k = 0; k < 8; ++k) L[swz(64 * k + t)] = r[k];
  {
    const int base = 64 * (t >> 3) + (t & 7);
    #pragma unroll
    for (int d = 0; d < 8; ++d) r[d] = L[swz(base + 8 * d)];
  }
  dft8<INV>(r);
  #pragma unroll
  for (int e = 1; e < 8; ++e) r[e] = cmul_s<INV>(r[e], tw64[e - 1]);
  {
    const int base = 64 * (t >> 3) + (t & 7);
    #pragma unroll
    for (int e = 0; e < 8; ++e) L[swz(base + 8 * e)] = r[e];
  }
  #pragma unroll
  for (int m = 0; m < 8; ++m) r[m] = L[swz(8 * t + m)];
  dft8<INV>(r);
}

// Mirror (DIT): digit-rev in -> natural out. INV=true gives 512*IDFT.
template<bool INV>
__device__ __forceinline__ void fft512_dit(float2 r[8], float2* __restrict__ L, int t,
                                           const float2 tw64[7]) {
  const float SG = INV ? TWOPI : -TWOPI;
  dft8<INV>(r);
  #pragma unroll
  for (int c = 1; c < 8; ++c) r[c] = cmul_s<INV>(r[c], tw64[c - 1]);
  #pragma unroll
  for (int c = 0; c < 8; ++c) L[swz(8 * t + c)] = r[c];
  {
    const int base = 64 * (t >> 3) + (t & 7);
    #pragma unroll
    for (int e = 0; e < 8; ++e) r[e] = L[swz(base + 8 * e)];
  }
  dft8<INV>(r);
  {
    const int k = t >> 3, c = t & 7;
    float2 w = cexpm(SG * (float)(c * k) * (1.0f / 512.0f));
    float2 st = cexpm(SG * (float)k * (1.0f / 64.0f));
    #pragma unroll
    for (int d = 0; d < 8; ++d) { r[d] = cmul(r[d], w); w = cmul(w, st); }
  }
  {
    const int base = 64 * (t >> 3) + (t & 7);
    #pragma unroll
    for (int d = 0; d < 8; ++d) L[swz(base + 8 * d)] = r[d];
  }
  #pragma unroll
  for (int j = 0; j < 8; ++j) r[j] = L[swz(64 * j + t)];
  dft8<INV>(r);
}

__device__ __forceinline__ int ringc(int u) { return (u < 256) ? (u + 1) : (512 - u); }

// Pass 1: two real rows packed per complex FFT -> Hermitian unpack -> store half
// spectrum transposed: W[u][h], u in [0,256]. Block covers 16 image rows.
__global__ __launch_bounds__(TPB) void k_fwd_real(const float* __restrict__ x,
                                                  float2* __restrict__ W,
                                                  int img0, int img_stride) {
  __shared__ float2 stg[8][SPITCH];
  const int g = threadIdx.x >> 6, t = threadIdx.x & 63;
  const int li = blockIdx.x >> 5;
  const int R0 = (blockIdx.x & 31) * 16;
  const int img = img0 + li * img_stride;
  const float* __restrict__ base = x + (size_t)img * (FN * FN);
  float2 tw512[7], tw64[7];
  build_tw(t, tw512, tw64);
  #pragma unroll
  for (int s = 0; s < 2; ++s) {
    const int pr = 4 * s + g;                       // packed-row index (2 image rows)
    const float* __restrict__ ra = base + (size_t)(R0 + 2 * pr) * FN;
    const float* __restrict__ rb = ra + FN;
    float2 r[8];
    #pragma unroll
    for (int j = 0; j < 8; ++j) r[j] = make_float2(ra[t + 64 * j], rb[t + 64 * j]);
    fft512_dif<false>(r, &stg[pr][0], t, tw512, tw64);
    #pragma unroll
    for (int f = 0; f < 8; ++f) stg[pr][64 * f + 8 * (t & 7) + (t >> 3)] = r[f];
  }
  __syncthreads();
  float2* __restrict__ dst = W + (size_t)li * (WACOLS * FN);
  const int pr = threadIdx.x & 7;
  const int u0 = threadIdx.x >> 3;                  // 0..31
  #pragma unroll
  for (int kk = 0; kk < 8; ++kk) {
    int u = u0 + 32 * kk;                           // 0..255
    float2 Za = stg[pr][u];
    float2 Zb = stg[pr][(512 - u) & 511];
    // F_a[u] = (Z[u]+conj(Z[-u]))/2 ; F_b[u] = (Z[u]-conj(Z[-u]))/(2i)
    float2 Fa = make_float2(0.5f * (Za.x + Zb.x), 0.5f * (Za.y - Zb.y));
    float2 Fb = make_float2(0.5f * (Za.y + Zb.y), 0.5f * (Zb.x - Za.x));
    float4* d4 = (float4*)(dst + (size_t)u * FN + R0 + 2 * pr);
    *d4 = make_float4(Fa.x, Fa.y, Fb.x, Fb.y);
  }
  if (threadIdx.x < 8) {                            // u = 256 (self-paired Nyquist)
    float2 Z = stg[threadIdx.x][256];
    float4* d4 = (float4*)(dst + (size_t)256 * FN + R0 + 2 * threadIdx.x);
    *d4 = make_float4(Z.x, 0.f, Z.y, 0.f);
  }
}

// Pre-pass: column FFTs on channel-0 half-spectra; bin |S|^2 (and Hermitian mirror)
// into square rings, fixed-point (order-invariant).
__global__ __launch_bounds__(TPB) void k_ring(const float2* __restrict__ W1p, ull* __restrict__ bins) {
  __shared__ float2 ex[4][FN];
  __shared__ ull lbins[NBINS];
  const int g = threadIdx.x >> 6, t = threadIdx.x & 63;
  for (int i = threadIdx.x; i < NBINS; i += TPB) lbins[i] = 0;
  __syncthreads();
  const int li = blockIdx.x / 33;
  const int U0 = (blockIdx.x % 33) * 8;
  const float2* __restrict__ src = W1p + (size_t)li * (WACOLS * FN);
  float2 tw512[7], tw64[7];
  build_tw(t, tw512, tw64);
  #pragma unroll
  for (int s = 0; s < 2; ++s) {
    const int u = U0 + 4 * s + g;
    if (u > 256) continue;
    const float2* __restrict__ row = src + (size_t)u * FN;
    float2 r[8];
    #pragma unroll
    for (int j = 0; j < 8; ++j) r[j] = row[t + 64 * j];
    fft512_dif<false>(r, &ex[g][0], t, tw512, tw64);
    const int cu = ringc(u);
    const bool mir = (u >= 1 && u <= 255);
    const int cmu = mir ? ringc(512 - u) : 0;
    #pragma unroll
    for (int f = 0; f < 8; ++f) {
      int v = 64 * f + 8 * (t & 7) + (t >> 3);
      float e = fmaf(r[f].x, r[f].x, r[f].y * r[f].y);
      ull q = (ull)((double)e * 1048576.0);
      atomicAdd(&lbins[max(cu, ringc(v))], q);
      if (mir) atomicAdd(&lbins[max(cmu, ringc((512 - v) & 511))], q);
    }
  }
  __syncthreads();
  for (int i = threadIdx.x; i < NBINS; i += TPB)
    if (lbins[i]) atomicAdd(&bins[(size_t)li * NBINS + i], lbins[i]);
}

__global__ __launch_bounds__(64) void k_cutoff(const ull* __restrict__ bins, int* __restrict__ cut) {
  int b = threadIdx.x;
  if (b >= NBATCH) return;
  double tot = 0.0;
  for (int r = 0; r < NBINS; ++r) tot += (double)bins[b * NBINS + r];
  double target = 0.5 * tot;
  double cum = 0.0;
  int c = 5;
  bool found = false;
  for (int r = 0; r <= 255; ++r) {
    cum += (double)bins[b * NBINS + r];
    if (r >= 1 && !found && cum >= target) { c = r; found = true; }
  }
  cut[b] = c;
}

// Pass 2 (LOW band only): for columns u with c(u)<=cut, column FFT -> keep low v
// (scaled 1/512) -> inverse column FFT -> transposed store Wb[h][u]. Columns from
// the Hermitian half via conj. Fully-high blocks exit; garbage in skipped columns
// is masked out by pass 3.
__global__ __launch_bounds__(TPB) void k_mask(const float2* __restrict__ Wa, float2* __restrict__ Wb,
                                              const int* __restrict__ cut, int img0) {
  __shared__ float2 stg[8][SPITCH];
  const int g = threadIdx.x >> 6, t = threadIdx.x & 63;
  const int li = blockIdx.x >> 6;
  const int U0 = (blockIdx.x & 63) * 8;
  const int cutoff = cut[(img0 + li) >> 5];
  bool anyLow = false;
  #pragma unroll
  for (int i = 0; i < 8; ++i) anyLow |= (ringc(U0 + i) <= cutoff);
  if (!anyLow) return;
  const float2* __restrict__ src = Wa + (size_t)li * (WACOLS * FN);
  float2 tw512[7], tw64[7];
  build_tw(t, tw512, tw64);
  const float sc = 1.0f / 512.0f;
  #pragma unroll
  for (int s = 0; s < 2; ++s) {
    const int rl = 4 * s + g;
    const int u = U0 + rl;
    if (ringc(u) > cutoff) continue;
    const bool mirror = (u > 256);
    const float2* __restrict__ row = src + (size_t)(mirror ? 512 - u : u) * FN;
    float2 r[8];
    #pragma unroll
    for (int j = 0; j < 8; ++j) {
      r[j] = row[t + 64 * j];
      if (mirror) r[j].y = -r[j].y;     // F[h, u] = conj(F[h, 512-u])
    }
    float2* L = &stg[rl][0];
    fft512_dif<false>(r, L, t, tw512, tw64);
    #pragma unroll
    for (int f = 0; f < 8; ++f) {
      int v = 64 * f + 8 * (t & 7) + (t >> 3);
      if (ringc(v) <= cutoff) { r[f].x *= sc; r[f].y *= sc; }
      else r[f] = make_float2(0.f, 0.f);
    }
    fft512_dit<true>(r, L, t, tw64);
    #pragma unroll
    for (int j = 0; j < 8; ++j) stg[rl][t + 64 * j] = r[j];
  }
  __syncthreads();
  float2* __restrict__ dst = Wb + (size_t)li * (FN * FN);
  const int rl2 = threadIdx.x & 3;
  const int hg = threadIdx.x >> 2;
  #pragma unroll
  for (int k = 0; k < 8; ++k) {
    int h = hg + 64 * k;
    float2 a = stg[2 * rl2][h];
    float2 b = stg[2 * rl2 + 1][h];
    float4* d4 = (float4*)(dst + (size_t)h * FN + U0 + 2 * rl2);
    *d4 = make_float4(a.x, a.y, b.x, b.y);
  }
}

// Pass 3: u-mask (NaN-safe select kills stale columns) -> inverse row FFT of the
// low band -> out = |x - low| (digit-rev positions, 256B windows).
__global__ __launch_bounds__(TPB) void k_inv_abs(const float2* __restrict__ Wb,
                                                 const float* __restrict__ x,
                                                 float* __restrict__ out,
                                                 const int* __restrict__ cut, int img0) {
  __shared__ float2 ex[4][FN];
  const int g = threadIdx.x >> 6, t = threadIdx.x & 63;
  const int li = blockIdx.x >> 6;
  const int H0 = (blockIdx.x & 63) * 8;
  const int img = img0 + li;
  const int cutoff = cut[img >> 5];
  const float2* __restrict__ src = Wb + (size_t)li * (FN * FN);
  const float* __restrict__ xbase = x + (size_t)img * (FN * FN);
  float* __restrict__ obase = out + (size_t)img * (FN * FN);
  float2 tw512[7], tw64[7];
  build_tw(t, tw512, tw64);
  const float sc = 1.0f / 512.0f;
  #pragma unroll
  for (int s = 0; s < 2; ++s) {
    const int h = H0 + 4 * s + g;
    const float2* __restrict__ row = src + (size_t)h * FN;
    float2 r[8];
    #pragma unroll
    for (int j = 0; j < 8; ++j) {
      int u = t + 64 * j;
      float2 v = row[u];
      r[j] = (ringc(u) <= cutoff) ? make_float2(v.x * sc, v.y * sc)
                                  : make_float2(0.f, 0.f);
    }
    fft512_dif<true>(r, &ex[g][0], t, tw512, tw64);
    const float* __restrict__ xrow = xbase + (size_t)h * FN;
    float* __restrict__ orow = obase + (size_t)h * FN;
    #pragma unroll
    for (int f = 0; f < 8; ++f) {
      int p = 64 * f + 8 * (t & 7) + (t >> 3);
      float xv = xrow[p];
      float re = xv - r[f].x;
      orow[p] = sqrtf(fmaf(re, re, r[f].y * r[f].y));
    }
  }
}

extern "C" void kernel_launch(void* const* d_in, const int* in_sizes, int n_in,
                              void* d_out, int out_size, void* d_ws, size_t ws_size,
                              hipStream_t stream) {
  const float* x = (const float*)d_in[0];
  float* out = (float*)d_out;
  char* ws = (char*)d_ws;

  size_t off = 0;
  ull* bins = (ull*)(ws + off);
  off += ((size_t)NBATCH * NBINS * sizeof(ull) + 255) & ~(size_t)255;
  int* cut = (int*)(ws + off);
  off += 256;
  float2* W1p = (float2*)(ws + off);
  off += (size_t)NBATCH * WACOLS * FN * sizeof(float2);   // 8.4 MiB

  const size_t per_wa = (size_t)WACOLS * FN * sizeof(float2);  // ~1.03 MiB
  const size_t per_wb = (size_t)FN * FN * sizeof(float2);      // 2 MiB
  size_t avail = (ws_size > off) ? (ws_size - off) : 0;
  int K = (int)(avail / (per_wa + per_wb));
  if (K > 32) K = 32;   // keep WA+WB+x-chunk+out-chunk L3-resident
  if (K < 1) K = 1;
  float2* WA = (float2*)(ws + off);
  float2* WB = (float2*)(ws + off + (size_t)K * per_wa);

  hipMemsetAsync(bins, 0, (size_t)NBATCH * NBINS * sizeof(ull), stream);

  // Pre-pass on the 8 channel-0 images: half-spectrum + ring energies + cutoffs.
  hipLaunchKernelGGL(k_fwd_real, dim3(NBATCH * 32), dim3(TPB), 0, stream, x, W1p, 0, NCH);
  hipLaunchKernelGGL(k_ring,     dim3(NBATCH * 33), dim3(TPB), 0, stream, W1p, bins);
  hipLaunchKernelGGL(k_cutoff,   dim3(1),           dim3(64),  0, stream, bins, cut);

  // Main pipeline, chunked for L3 residency.
  for (int c0 = 0; c0 < NIMG; c0 += K) {
    int nk = (NIMG - c0 < K) ? (NIMG - c0) : K;
    hipLaunchKernelGGL(k_fwd_real, dim3(nk * 32), dim3(TPB), 0, stream, x, WA, c0, 1);
    hipLaunchKernelGGL(k_mask,     dim3(nk * 64), dim3(TPB), 0, stream, WA, WB, cut, c0);
    hipLaunchKernelGGL(k_inv_abs,  dim3(nk * 64), dim3(TPB), 0, stream, WB, x, out, cut, c0);
  }
}